// Round 13
// baseline (146.666 us; speedup 1.0000x reference)
//
#include <hip/hip_runtime.h>
#include <hip/hip_cooperative_groups.h>
#include <stdint.h>

namespace cg = cooperative_groups;

// N=16384 points, K=10 (fixed by setup_inputs).
#define NPTS   16384
#define TOPK   10
#define NBX    32                 // 32x32x32 cells over [-5,5]^3
#define NBK    (32 * 32 * 32)
#define XMIN   (-5.0f)
#define INVBW  (3.2f)             // 32 / 10.0
#define SENT_STEP 0x4000u         // one ulp at masked-key granularity (= idx field)
#define NSLOT  256                // padded accumulator rows (128 B apart)
#define PRE_BLOCKS 64             // cooperative preprocess grid

// ws layout (bytes):
//   128     parts[NSLOT][32] floats; [0]=sparsity [1]=scale [2]=opacity [3]=smooth
//   33024   hist[NBK] uint                                [33024, 164096)
//   164096  blocksum[PRE_BLOCKS] uint                     [164096, 164352)
//   164352  base[NBK+1] uint                              [164352, 295428)
//   295552  sorted[NPTS] float4 (x,y,z,opacity) cell-order
// memset zeroes [0, 164096) = parts + hist. blocksum/base/sorted are fully
// written before read. Cross-block ordering ONLY via cg::grid sync (G16-safe;
// r11's hand-rolled spin barrier deadlocked and is permanently retired).

__device__ __forceinline__ unsigned umin_(unsigned a, unsigned b) { return a < b ? a : b; }
__device__ __forceinline__ unsigned umax_(unsigned a, unsigned b) { return a > b ? a : b; }

// Branchless ascending insert (19 independent min/max).
__device__ __forceinline__ void chain_insert(unsigned a[TOPK], unsigned key) {
#pragma unroll
    for (int k = TOPK - 1; k > 0; --k) a[k] = umin_(umax_(a[k - 1], key), a[k]);
    a[0] = umin_(a[0], key);
}

__device__ __forceinline__ void ce_(unsigned &x, unsigned &y) {
    unsigned lo = umin_(x, y); y = umax_(x, y); x = lo;
}

// Bitonic merge network for a length-10 bitonic sequence (15 CEs).
__device__ __forceinline__ void bitonic10(unsigned a[TOPK]) {
    ce_(a[0], a[8]); ce_(a[1], a[9]);
    ce_(a[0], a[4]); ce_(a[1], a[5]); ce_(a[2], a[6]); ce_(a[3], a[7]);
    ce_(a[0], a[2]); ce_(a[1], a[3]); ce_(a[4], a[6]); ce_(a[5], a[7]);
    ce_(a[0], a[1]); ce_(a[2], a[3]); ce_(a[4], a[5]); ce_(a[6], a[7]); ce_(a[8], a[9]);
}

// Merge two sorted 10-lists: ours + partner lane's (halver + bitonic net).
__device__ __forceinline__ void merge_shfl(unsigned a[TOPK], int w) {
    unsigned b[TOPK];
#pragma unroll
    for (int k = 0; k < TOPK; ++k) b[k] = (unsigned)__shfl_xor((int)a[k], w, 64);
#pragma unroll
    for (int k = 0; k < TOPK; ++k) a[k] = umin_(a[k], b[TOPK - 1 - k]);
    bitonic10(a);
}

// Process two candidates with both loads issued before either use.
__device__ __forceinline__ void scan2(
    unsigned a[TOPK], const float4* __restrict__ sorted,
    unsigned p0, unsigned p1, unsigned s, float mx, float my, float mz)
{
    float4 c0 = sorted[p0];
    float4 c1 = sorted[p1];
    float dx0 = c0.x - mx, dy0 = c0.y - my, dz0 = c0.z - mz;
    float dx1 = c1.x - mx, dy1 = c1.y - my, dz1 = c1.z - mz;
    float d20 = fmaf(dx0, dx0, fmaf(dy0, dy0, dz0 * dz0));
    float d21 = fmaf(dx1, dx1, fmaf(dy1, dy1, dz1 * dz1));
    unsigned k0 = (__float_as_uint(d20) & 0xFFFFC000u) | p0;
    unsigned k1 = (__float_as_uint(d21) & 0xFFFFC000u) | p1;
    if (p0 == s) k0 = 0xFFFFFFFFu;
    if (p1 == s) k1 = 0xFFFFFFFFu;
    unsigned kmin = umin_(k0, k1), kmax = umax_(k0, k1);
    if (kmin < a[TOPK - 1]) {
        chain_insert(a, kmin);
        if (kmax < a[TOPK - 1]) chain_insert(a, kmax);
    }
}

__device__ __forceinline__ void scan1(
    unsigned a[TOPK], const float4* __restrict__ sorted,
    unsigned p, unsigned s, float mx, float my, float mz)
{
    float4 c = sorted[p];
    float dx = c.x - mx, dy = c.y - my, dz = c.z - mz;
    float d2 = fmaf(dx, dx, fmaf(dy, dy, dz * dz));
    unsigned key = (__float_as_uint(d2) & 0xFFFFC000u) | p;
    if (p == s) key = 0xFFFFFFFFu;
    if (key < a[TOPK - 1]) chain_insert(a, key);
}

__device__ __forceinline__ int cellf(float v) {
    int b = (int)((v - XMIN) * INVBW);
    return min(max(b, 0), NBX - 1);
}

// ---- cooperative preprocess: losses + hist + scan + scatter ---------------
// 64 blocks x 256 threads = one thread per point. Rank within cell comes from
// the histogram atomic's return value and stays in registers (no bidx array).
// Cross-block phases ordered by cg::this_grid().sync().
__global__ __launch_bounds__(256) void preprocess(
    const float* __restrict__ pos, const float* __restrict__ opac,
    const float* __restrict__ scales, float* __restrict__ parts,
    unsigned* __restrict__ hist, unsigned* __restrict__ blocksum,
    unsigned* __restrict__ base, float4* __restrict__ sorted)
{
    cg::grid_group grid = cg::this_grid();
    const int tid  = blockIdx.x * 256 + threadIdx.x;     // 0..16383
    const int lane = threadIdx.x & 63;
    const int wv   = threadIdx.x >> 6;

    // ---- phase 1: trivial losses + histogram + rank ----
    const float x = pos[3 * tid], y = pos[3 * tid + 1], z = pos[3 * tid + 2];
    const float o = opac[tid];
    float d = o - 0.5f;
    float s_sp = fabsf(o);
    float s_op = d * d;
    float s_sc = fabsf(scales[3 * tid] - 1.0f) + fabsf(scales[3 * tid + 1] - 1.0f)
               + fabsf(scales[3 * tid + 2] - 1.0f);
    const int b = (cellf(x) << 10) | (cellf(y) << 5) | cellf(z);
    const unsigned rank = atomicAdd(&hist[b], 1u);       // return = rank in cell
#pragma unroll
    for (int off = 32; off > 0; off >>= 1) {
        s_sp += __shfl_down(s_sp, off, 64);
        s_sc += __shfl_down(s_sc, off, 64);
        s_op += __shfl_down(s_op, off, 64);
    }
    if (lane == 0) {
        const int row = (blockIdx.x * 4 + wv) & (NSLOT - 1);
        atomicAdd(&parts[row * 32 + 0], s_sp);
        atomicAdd(&parts[row * 32 + 1], s_sc);
        atomicAdd(&parts[row * 32 + 2], s_op);
    }

    grid.sync();                                         // hist complete

    // ---- phase 2a: per-thread 2-bin scan + block sums ----
    const unsigned h0 = hist[2 * tid], h1 = hist[2 * tid + 1];
    const unsigned tot = h0 + h1;
    unsigned inc = tot;
#pragma unroll
    for (int off = 1; off < 64; off <<= 1) {
        unsigned v = (unsigned)__shfl_up((int)inc, off, 64);
        if (lane >= off) inc += v;
    }
    __shared__ unsigned lws[4];
    __shared__ unsigned s_bpref;
    if (lane == 63) lws[wv] = inc;
    __syncthreads();
    unsigned woff = 0;
    for (int w = 0; w < wv; ++w) woff += lws[w];
    if (threadIdx.x == 0)
        blocksum[blockIdx.x] = lws[0] + lws[1] + lws[2] + lws[3];

    grid.sync();                                         // blocksum complete

    // ---- phase 2b: block prefix + base writes ----
    if (wv == 0) {
        unsigned bsv = blocksum[lane];                   // PRE_BLOCKS == 64 lanes
        unsigned mine = ((unsigned)lane < blockIdx.x) ? bsv : 0u;
#pragma unroll
        for (int off = 32; off > 0; off >>= 1)
            mine += (unsigned)__shfl_xor((int)mine, off, 64);
        if (lane == 0) s_bpref = mine;
    }
    __syncthreads();
    const unsigned tb = s_bpref + woff + (inc - tot);    // exclusive base
    base[2 * tid]     = tb;
    base[2 * tid + 1] = tb + h0;
    if (tid == NPTS - 1) base[NBK] = (unsigned)NPTS;

    grid.sync();                                         // base complete

    // ---- phase 3: scatter (no atomics; b/rank/x/y/z/o still in registers) --
    sorted[base[b] + rank] = make_float4(x, y, z, o);
}

// ---- unified kNN: ONE WAVE per point --------------------------------------
// Phase A bound: +/-128 cell-order window, 4 candidates/lane -> sort4 network
//   + INF pad, then the full 6-level wave merge (TIGHT bound -- r12's group
//   bound was looser and gave back the savings in phase-C window growth).
// Phase B: all column-pair bounds loaded lane-parallel into registers.
// Phase C: 8 groups of 8 lanes scan pairs j = g, g+8, ... with a 2-deep
//   pipelined run walk; 6-level merge converges the wave; smoothness gather;
//   one padded-slot atomic per wave.
__global__ __launch_bounds__(256) void knn_all(
    const float4* __restrict__ sorted, const unsigned* __restrict__ base,
    float* __restrict__ parts)
{
    const int lane = threadIdx.x & 63;
    const int s    = (blockIdx.x * 256 + threadIdx.x) >> 6;   // wave id = point

    const float4 me = sorted[s];

    // ---- phase A: bound ----
    unsigned kk[4];
    {
        const int dir = lane >> 5;              // 0 right, 1 left
        const int start = 1 + (lane & 31) * 4;
#pragma unroll
        for (int t = 0; t < 4; ++t) {
            int p = dir ? (s - start - t) : (s + start + t);
            int pc = min(max(p, 0), NPTS - 1);
            float4 c = sorted[pc];
            float dx = c.x - me.x, dy = c.y - me.y, dz = c.z - me.z;
            float d2 = fmaf(dx, dx, fmaf(dy, dy, dz * dz));
            unsigned key = (__float_as_uint(d2) & 0xFFFFC000u) | (unsigned)pc;
            if (p < 0 || p >= NPTS) key = 0xFFFFFFFFu;
            kk[t] = key;
        }
    }
    // sort4 network (5 CEs) + INF pad replaces 4 chain_inserts
    ce_(kk[0], kk[2]); ce_(kk[1], kk[3]); ce_(kk[0], kk[1]);
    ce_(kk[2], kk[3]); ce_(kk[1], kk[2]);
    unsigned a[TOPK];
    a[0] = kk[0]; a[1] = kk[1]; a[2] = kk[2]; a[3] = kk[3];
#pragma unroll
    for (int k = 4; k < TOPK; ++k) a[k] = 0xFFFFFFFFu;
    merge_shfl(a, 1);  merge_shfl(a, 2);  merge_shfl(a, 4);
    merge_shfl(a, 8);  merge_shfl(a, 16); merge_shfl(a, 32);
    const unsigned sentinel = (a[TOPK - 1] & 0xFFFFC000u) + SENT_STEP;
    const float R = sqrtf(__uint_as_float(sentinel)) + 1e-6f;

    const int bxlo = cellf(me.x - R), bxhi = cellf(me.x + R);
    const int bylo = cellf(me.y - R), byhi = cellf(me.y + R);
    const int bzlo = cellf(me.z - R), bzhi = cellf(me.z + R);
    const int nyw   = byhi - bylo + 1;
    const int npair = (bxhi - bxlo + 1) * nyw;

    // ---- phase B/C: lane-parallel bounds + group-parallel pair scan ----
#pragma unroll
    for (int k = 0; k < TOPK; ++k) a[k] = sentinel;

    const int grp = lane >> 3;                  // group 0..7
    const int gl  = lane & 7;                   // lane in group

    for (int cbase = 0; cbase < npair; cbase += 64) {
        const int cnum = min(64, npair - cbase);
        unsigned mylo = 0, myhi = 0;
        const int pi = cbase + lane;
        if (pi < npair) {
            const int qx = pi / nyw;
            const int cb = ((bxlo + qx) << 10) | ((bylo + pi - qx * nyw) << 5);
            mylo = base[cb + bzlo];
            myhi = base[cb + bzhi + 1];
        }
        for (int j = grp; j < cnum; j += 8) {
            const unsigned lo = (unsigned)__shfl((int)mylo, j, 64);
            const unsigned hi = (unsigned)__shfl((int)myhi, j, 64);
            unsigned p = lo + gl;
            for (; p + 8 < hi; p += 16)
                scan2(a, sorted, p, p + 8, (unsigned)s, me.x, me.y, me.z);
            if (p < hi)
                scan1(a, sorted, p, (unsigned)s, me.x, me.y, me.z);
        }
    }

    merge_shfl(a, 1);  merge_shfl(a, 2);  merge_shfl(a, 4);
    merge_shfl(a, 8);  merge_shfl(a, 16); merge_shfl(a, 32);

    float v = 0.0f;
    if (lane < TOPK) {
        int j = (int)(a[lane] & 0x3FFFu);
        v = fabsf(me.w - sorted[j].w);
    }
    v += __shfl_down(v, 8, 64);
    v += __shfl_down(v, 4, 64);
    v += __shfl_down(v, 2, 64);
    v += __shfl_down(v, 1, 64);
    if (lane == 0)
        atomicAdd(&parts[(s & (NSLOT - 1)) * 32 + 3], v);
}

// ---- combine --------------------------------------------------------------
__global__ void combine(const float* __restrict__ parts, float* __restrict__ out)
{
    const int lane = threadIdx.x;                // 64 threads
    float sp = 0.0f, sc = 0.0f, op = 0.0f, sm = 0.0f;
#pragma unroll
    for (int r = 0; r < NSLOT / 64; ++r) {
        float4 p = *(const float4*)(parts + (r * 64 + lane) * 32);
        sp += p.x; sc += p.y; op += p.z; sm += p.w;
    }
#pragma unroll
    for (int off = 32; off > 0; off >>= 1) {
        sp += __shfl_down(sp, off, 64);
        sc += __shfl_down(sc, off, 64);
        op += __shfl_down(op, off, 64);
        sm += __shfl_down(sm, off, 64);
    }
    if (lane == 0) {
        const float n = (float)NPTS;
        out[0] = 0.01f * (sp / n) + 0.1f * (sm / (n * 10.0f))
               + sc / (3.0f * n) + op / n;
    }
}

extern "C" void kernel_launch(void* const* d_in, const int* in_sizes, int n_in,
                              void* d_out, int out_size, void* d_ws, size_t ws_size,
                              hipStream_t stream)
{
    const float* pos    = (const float*)d_in[0];
    const float* opac   = (const float*)d_in[1];
    const float* scales = (const float*)d_in[2];
    float* out = (float*)d_out;

    char* ws = (char*)d_ws;
    float*    parts    = (float*)(ws + 128);
    unsigned* hist     = (unsigned*)(ws + 33024);
    unsigned* blocksum = (unsigned*)(ws + 164096);
    unsigned* base     = (unsigned*)(ws + 164352);
    float4*   sorted   = (float4*)(ws + 295552);

    hipMemsetAsync(ws, 0, 164096, stream);

    void* args[] = { (void*)&pos, (void*)&opac, (void*)&scales, (void*)&parts,
                     (void*)&hist, (void*)&blocksum, (void*)&base, (void*)&sorted };
    hipLaunchCooperativeKernel(preprocess, dim3(PRE_BLOCKS), dim3(256),
                               args, 0, stream);

    knn_all<<<NPTS / 4, 256, 0, stream>>>(sorted, base, parts);
    combine<<<1, 64, 0, stream>>>(parts, out);
}

// Round 14
// 111.859 us; speedup vs baseline: 1.3112x; 1.3112x over previous
//
#include <hip/hip_runtime.h>
#include <stdint.h>

// N=16384 points, K=10 (fixed by setup_inputs).
#define NPTS   16384
#define TOPK   10
#define NBX    32                 // 32x32x32 cells over [-5,5]^3
#define NBK    (32 * 32 * 32)
#define XMIN   (-5.0f)
#define INVBW  (3.2f)             // 32 / 10.0
#define SENT_STEP 0x4000u         // one ulp at masked-key granularity (= idx field)
#define NSLOT  256                // padded accumulator rows (128 B apart)

// ws layout (bytes):
//   128     parts[NSLOT][32] floats; row: [0]=sparsity [1]=scale [2]=opacity
//           [3]=smooth                                  [128, 32896)
//   33024   hist[NBK] uint -> re-zeroed by scan, reused as cnt [33024, 164096)
//   164096  base[NBK+1] uint                            [164096, 295172)
//   295296  sorted[NPTS] float4 (x,y,z,opacity) cell-order
// memset zeroes [0, 164096). No with-return atomics anywhere; all float
// accumulation goes to padded rows (<= 64 RMWs per address).
// r11: hand-rolled grid barrier deadlocked (G16). r13: cooperative launch
// cost +31 us under graph capture. Both fusion routes retired; 5-kernel
// pipeline (r10 structure) is final.

__device__ __forceinline__ unsigned umin_(unsigned a, unsigned b) { return a < b ? a : b; }
__device__ __forceinline__ unsigned umax_(unsigned a, unsigned b) { return a > b ? a : b; }

// Branchless ascending insert (19 independent min/max).
__device__ __forceinline__ void chain_insert(unsigned a[TOPK], unsigned key) {
#pragma unroll
    for (int k = TOPK - 1; k > 0; --k) a[k] = umin_(umax_(a[k - 1], key), a[k]);
    a[0] = umin_(a[0], key);
}

__device__ __forceinline__ void ce_(unsigned &x, unsigned &y) {
    unsigned lo = umin_(x, y); y = umax_(x, y); x = lo;
}

// Bitonic merge network for a length-10 bitonic sequence (15 CEs).
__device__ __forceinline__ void bitonic10(unsigned a[TOPK]) {
    ce_(a[0], a[8]); ce_(a[1], a[9]);
    ce_(a[0], a[4]); ce_(a[1], a[5]); ce_(a[2], a[6]); ce_(a[3], a[7]);
    ce_(a[0], a[2]); ce_(a[1], a[3]); ce_(a[4], a[6]); ce_(a[5], a[7]);
    ce_(a[0], a[1]); ce_(a[2], a[3]); ce_(a[4], a[5]); ce_(a[6], a[7]); ce_(a[8], a[9]);
}

// Merge two sorted 10-lists: ours + partner lane's (halver + bitonic net).
__device__ __forceinline__ void merge_shfl(unsigned a[TOPK], int w) {
    unsigned b[TOPK];
#pragma unroll
    for (int k = 0; k < TOPK; ++k) b[k] = (unsigned)__shfl_xor((int)a[k], w, 64);
#pragma unroll
    for (int k = 0; k < TOPK; ++k) a[k] = umin_(a[k], b[TOPK - 1 - k]);
    bitonic10(a);
}

// Process two candidates with both loads issued before either use.
__device__ __forceinline__ void scan2(
    unsigned a[TOPK], const float4* __restrict__ sorted,
    unsigned p0, unsigned p1, unsigned s, float mx, float my, float mz)
{
    float4 c0 = sorted[p0];
    float4 c1 = sorted[p1];
    float dx0 = c0.x - mx, dy0 = c0.y - my, dz0 = c0.z - mz;
    float dx1 = c1.x - mx, dy1 = c1.y - my, dz1 = c1.z - mz;
    float d20 = fmaf(dx0, dx0, fmaf(dy0, dy0, dz0 * dz0));
    float d21 = fmaf(dx1, dx1, fmaf(dy1, dy1, dz1 * dz1));
    unsigned k0 = (__float_as_uint(d20) & 0xFFFFC000u) | p0;
    unsigned k1 = (__float_as_uint(d21) & 0xFFFFC000u) | p1;
    if (p0 == s) k0 = 0xFFFFFFFFu;
    if (p1 == s) k1 = 0xFFFFFFFFu;
    unsigned kmin = umin_(k0, k1), kmax = umax_(k0, k1);
    if (kmin < a[TOPK - 1]) {
        chain_insert(a, kmin);
        if (kmax < a[TOPK - 1]) chain_insert(a, kmax);
    }
}

__device__ __forceinline__ void scan1(
    unsigned a[TOPK], const float4* __restrict__ sorted,
    unsigned p, unsigned s, float mx, float my, float mz)
{
    float4 c = sorted[p];
    float dx = c.x - mx, dy = c.y - my, dz = c.z - mz;
    float d2 = fmaf(dx, dx, fmaf(dy, dy, dz * dz));
    unsigned key = (__float_as_uint(d2) & 0xFFFFC000u) | p;
    if (p == s) key = 0xFFFFFFFFu;
    if (key < a[TOPK - 1]) chain_insert(a, key);
}

__device__ __forceinline__ int cellf(float v) {
    int b = (int)((v - XMIN) * INVBW);
    return min(max(b, 0), NBX - 1);
}

// ---- fused trivial losses + 3-D cell histogram ----------------------------
__global__ __launch_bounds__(256) void setup_kernel(
    const float* __restrict__ pos, const float* __restrict__ opac,
    const float* __restrict__ scales, float* __restrict__ parts,
    unsigned* __restrict__ hist)
{
    int i = blockIdx.x * 256 + threadIdx.x;
    float o = opac[i];
    float d = o - 0.5f;
    float s_sp = fabsf(o);
    float s_op = d * d;
    float s_sc = fabsf(scales[3 * i] - 1.0f) + fabsf(scales[3 * i + 1] - 1.0f)
               + fabsf(scales[3 * i + 2] - 1.0f);
    int bx = cellf(pos[3 * i]);
    int by = cellf(pos[3 * i + 1]);
    int bz = cellf(pos[3 * i + 2]);
    atomicAdd(&hist[(bx << 10) | (by << 5) | bz], 1u);
#pragma unroll
    for (int off = 32; off > 0; off >>= 1) {
        s_sp += __shfl_down(s_sp, off, 64);
        s_sc += __shfl_down(s_sc, off, 64);
        s_op += __shfl_down(s_op, off, 64);
    }
    if ((threadIdx.x & 63) == 0) {
        const int row = (blockIdx.x * 4 + (threadIdx.x >> 6)) & (NSLOT - 1);
        atomicAdd(&parts[row * 32 + 0], s_sp);
        atomicAdd(&parts[row * 32 + 1], s_sc);
        atomicAdd(&parts[row * 32 + 2], s_op);
    }
}

// Exclusive scan over 32768 bins: shfl-based (2 barriers total).
// Also re-zeroes hist in place (it becomes the scatter cnt array).
__global__ __launch_bounds__(1024) void prefix_scan(
    unsigned* __restrict__ hist, unsigned* __restrict__ base)
{
    __shared__ unsigned wsum[16];
    const int t = threadIdx.x;
    const int lane = t & 63, wid = t >> 6;
    unsigned loc[32];
    uint4* h4 = (uint4*)(hist + t * 32);
#pragma unroll
    for (int j = 0; j < 8; ++j) {
        uint4 h = h4[j];
        loc[4 * j + 0] = h.x; loc[4 * j + 1] = h.y;
        loc[4 * j + 2] = h.z; loc[4 * j + 3] = h.w;
    }
    unsigned run = 0;
#pragma unroll
    for (int j = 0; j < 32; ++j) { unsigned v = loc[j]; loc[j] = run; run += v; }
    unsigned inc = run;
#pragma unroll
    for (int off = 1; off < 64; off <<= 1) {
        unsigned v = (unsigned)__shfl_up((int)inc, off, 64);
        if (lane >= off) inc += v;
    }
    if (lane == 63) wsum[wid] = inc;
    __syncthreads();
    if (wid == 0) {
        unsigned w = (lane < 16) ? wsum[lane] : 0u;
#pragma unroll
        for (int off = 1; off < 16; off <<= 1) {
            unsigned v = (unsigned)__shfl_up((int)w, off, 64);
            if (lane >= off) w += v;
        }
        if (lane < 16) wsum[lane] = w;
    }
    __syncthreads();
    const unsigned wbase = (wid > 0) ? wsum[wid - 1] : 0u;
    const unsigned tbase = wbase + inc - run;
    uint4* b4 = (uint4*)(base + t * 32);
#pragma unroll
    for (int j = 0; j < 8; ++j) {
        b4[j] = make_uint4(loc[4 * j] + tbase, loc[4 * j + 1] + tbase,
                           loc[4 * j + 2] + tbase, loc[4 * j + 3] + tbase);
        h4[j] = make_uint4(0u, 0u, 0u, 0u);
    }
    if (t == 1023) base[NBK] = NPTS;
}

__global__ __launch_bounds__(256) void scatter_sorted(
    const float* __restrict__ pos, const float* __restrict__ opac,
    const unsigned* __restrict__ base, unsigned* __restrict__ cnt,
    float4* __restrict__ sorted)
{
    int i = blockIdx.x * 256 + threadIdx.x;
    float x = pos[3 * i], y = pos[3 * i + 1], z = pos[3 * i + 2];
    int b = (cellf(x) << 10) | (cellf(y) << 5) | cellf(z);
    unsigned p = base[b] + atomicAdd(&cnt[b], 1u);
    sorted[p] = make_float4(x, y, z, opac[i]);
}

// ---- unified kNN: ONE WAVE per point --------------------------------------
// Phase A bound: +/-128 cell-order window, 4 candidates/lane -> sort4 network
//   (5 CEs) + INF pad, full 6-level wave merge (TIGHT bound; r12 showed the
//   cheaper group bound loses more in phase-C window growth than it saves).
// Phase B: all column-pair bounds loaded lane-parallel into registers.
// Phase C: 8 groups of 8 lanes scan pairs j = g, g+8, ... with a 2-deep
//   pipelined run walk; 6-level merge converges the wave; smoothness gather;
//   one padded-slot atomic per wave.
__global__ __launch_bounds__(256) void knn_all(
    const float4* __restrict__ sorted, const unsigned* __restrict__ base,
    float* __restrict__ parts)
{
    const int lane = threadIdx.x & 63;
    const int s    = (blockIdx.x * 256 + threadIdx.x) >> 6;   // wave id = point

    const float4 me = sorted[s];

    // ---- phase A: bound ----
    unsigned kk[4];
    {
        const int dir = lane >> 5;              // 0 right, 1 left
        const int start = 1 + (lane & 31) * 4;
#pragma unroll
        for (int t = 0; t < 4; ++t) {
            int p = dir ? (s - start - t) : (s + start + t);
            int pc = min(max(p, 0), NPTS - 1);
            float4 c = sorted[pc];
            float dx = c.x - me.x, dy = c.y - me.y, dz = c.z - me.z;
            float d2 = fmaf(dx, dx, fmaf(dy, dy, dz * dz));
            unsigned key = (__float_as_uint(d2) & 0xFFFFC000u) | (unsigned)pc;
            if (p < 0 || p >= NPTS) key = 0xFFFFFFFFu;
            kk[t] = key;
        }
    }
    // sort4 network (5 CEs) + INF pad replaces 4 chain_inserts (76 min/max)
    ce_(kk[0], kk[2]); ce_(kk[1], kk[3]); ce_(kk[0], kk[1]);
    ce_(kk[2], kk[3]); ce_(kk[1], kk[2]);
    unsigned a[TOPK];
    a[0] = kk[0]; a[1] = kk[1]; a[2] = kk[2]; a[3] = kk[3];
#pragma unroll
    for (int k = 4; k < TOPK; ++k) a[k] = 0xFFFFFFFFu;
    merge_shfl(a, 1);  merge_shfl(a, 2);  merge_shfl(a, 4);
    merge_shfl(a, 8);  merge_shfl(a, 16); merge_shfl(a, 32);
    const unsigned sentinel = (a[TOPK - 1] & 0xFFFFC000u) + SENT_STEP;
    const float R = sqrtf(__uint_as_float(sentinel)) + 1e-6f;

    const int bxlo = cellf(me.x - R), bxhi = cellf(me.x + R);
    const int bylo = cellf(me.y - R), byhi = cellf(me.y + R);
    const int bzlo = cellf(me.z - R), bzhi = cellf(me.z + R);
    const int nyw   = byhi - bylo + 1;
    const int npair = (bxhi - bxlo + 1) * nyw;

    // ---- phase B/C: lane-parallel bounds + group-parallel pair scan ----
#pragma unroll
    for (int k = 0; k < TOPK; ++k) a[k] = sentinel;

    const int grp = lane >> 3;                  // group 0..7
    const int gl  = lane & 7;                   // lane in group

    for (int cbase = 0; cbase < npair; cbase += 64) {
        const int cnum = min(64, npair - cbase);
        unsigned mylo = 0, myhi = 0;
        const int pi = cbase + lane;
        if (pi < npair) {
            const int qx = pi / nyw;
            const int cb = ((bxlo + qx) << 10) | ((bylo + pi - qx * nyw) << 5);
            mylo = base[cb + bzlo];
            myhi = base[cb + bzhi + 1];
        }
        for (int j = grp; j < cnum; j += 8) {
            const unsigned lo = (unsigned)__shfl((int)mylo, j, 64);
            const unsigned hi = (unsigned)__shfl((int)myhi, j, 64);
            unsigned p = lo + gl;
            for (; p + 8 < hi; p += 16)
                scan2(a, sorted, p, p + 8, (unsigned)s, me.x, me.y, me.z);
            if (p < hi)
                scan1(a, sorted, p, (unsigned)s, me.x, me.y, me.z);
        }
    }

    merge_shfl(a, 1);  merge_shfl(a, 2);  merge_shfl(a, 4);
    merge_shfl(a, 8);  merge_shfl(a, 16); merge_shfl(a, 32);

    float v = 0.0f;
    if (lane < TOPK) {
        int j = (int)(a[lane] & 0x3FFFu);
        v = fabsf(me.w - sorted[j].w);
    }
    v += __shfl_down(v, 8, 64);
    v += __shfl_down(v, 4, 64);
    v += __shfl_down(v, 2, 64);
    v += __shfl_down(v, 1, 64);
    if (lane == 0)
        atomicAdd(&parts[(s & (NSLOT - 1)) * 32 + 3], v);
}

// ---- combine --------------------------------------------------------------
__global__ void combine(const float* __restrict__ parts, float* __restrict__ out)
{
    const int lane = threadIdx.x;                // 64 threads
    float sp = 0.0f, sc = 0.0f, op = 0.0f, sm = 0.0f;
#pragma unroll
    for (int r = 0; r < NSLOT / 64; ++r) {
        float4 p = *(const float4*)(parts + (r * 64 + lane) * 32);
        sp += p.x; sc += p.y; op += p.z; sm += p.w;
    }
#pragma unroll
    for (int off = 32; off > 0; off >>= 1) {
        sp += __shfl_down(sp, off, 64);
        sc += __shfl_down(sc, off, 64);
        op += __shfl_down(op, off, 64);
        sm += __shfl_down(sm, off, 64);
    }
    if (lane == 0) {
        const float n = (float)NPTS;
        out[0] = 0.01f * (sp / n) + 0.1f * (sm / (n * 10.0f))
               + sc / (3.0f * n) + op / n;
    }
}

extern "C" void kernel_launch(void* const* d_in, const int* in_sizes, int n_in,
                              void* d_out, int out_size, void* d_ws, size_t ws_size,
                              hipStream_t stream)
{
    const float* pos    = (const float*)d_in[0];
    const float* opac   = (const float*)d_in[1];
    const float* scales = (const float*)d_in[2];
    float* out = (float*)d_out;

    char* ws = (char*)d_ws;
    float*    parts  = (float*)(ws + 128);
    unsigned* histcnt= (unsigned*)(ws + 33024);    // hist -> cnt
    unsigned* base   = (unsigned*)(ws + 164096);
    float4*   sorted = (float4*)(ws + 295296);

    hipMemsetAsync(ws, 0, 164096, stream);

    setup_kernel  <<<NPTS / 256, 256, 0, stream>>>(pos, opac, scales, parts, histcnt);
    prefix_scan   <<<1, 1024, 0, stream>>>(histcnt, base);
    scatter_sorted<<<NPTS / 256, 256, 0, stream>>>(pos, opac, base, histcnt, sorted);
    knn_all       <<<NPTS / 4, 256, 0, stream>>>(sorted, base, parts);
    combine       <<<1, 64, 0, stream>>>(parts, out);
}